// Round 2
// baseline (2193.028 us; speedup 1.0000x reference)
//
#include <hip/hip_runtime.h>
#include <hip/hip_bf16.h>
#include <stdint.h>

typedef __hip_bfloat16 bf16;

__device__ __forceinline__ float b2f(bf16 x) { return __bfloat162float(x); }
__device__ __forceinline__ float bits2f(uint32_t u) {
    union { uint32_t i; float f; } c; c.i = u; return c.f;
}

// ---------------------------------------------------------------------------
// Mode detection: read even-indexed uint16s of nfeats as bf16. True bf16 data
// (N(0,1) samples) is ~100% "sane"; f32 data's low halves have mantissa bits
// in the exponent field -> ~9% sane. flag: 0 = bf16 inputs, 1 = f32 inputs.
// ---------------------------------------------------------------------------
__global__ void detect_mode_kernel(const uint16_t* __restrict__ nf, int* __restrict__ flag) {
    if (threadIdx.x != 0 || blockIdx.x != 0) return;
    int sane = 0;
    for (int i = 0; i < 256; ++i) {
        uint32_t u = nf[2 * i];
        float a = fabsf(bits2f(u << 16));
        if (a == 0.f || (a > 1e-5f && a < 100.f)) ++sane;
    }
    flag[0] = (sane >= 128) ? 0 : 1;
}

// ---------------------------------------------------------------------------
// Convert all 14 weight tensors to f32 scratch (single code path downstream).
// ---------------------------------------------------------------------------
struct ParamTable {
    const void* src[14];
    int off[15];   // off[14] = total
};

__global__ void convert_params_kernel(ParamTable T, const int* __restrict__ mode,
                                      float* __restrict__ out) {
    int i = blockIdx.x * blockDim.x + threadIdx.x;
    if (i >= T.off[14]) return;
    int k = 0;
    while (k < 13 && i >= T.off[k + 1]) ++k;
    int j = i - T.off[k];
    float v = (*mode == 0) ? b2f(((const bf16*)T.src[k])[j])
                           : ((const float*)T.src[k])[j];
    out[i] = v;
}

// wae[d*3+h] = sum_f We[d*96 + h*32 + f] * ae[h*32 + f]
__global__ void fold_wae_kernel(const float* __restrict__ We, const float* __restrict__ ae,
                                float* __restrict__ wae) {
    int t = threadIdx.x;
    if (t >= 96) return;
    int d = t / 3, h = t - d * 3;
    float acc = 0.f;
    for (int f = 0; f < 32; ++f)
        acc += We[d * 96 + h * 32 + f] * ae[h * 32 + f];
    wae[t] = acc;
}

// ---------------------------------------------------------------------------
// Per node (8 nodes/block): ft = x @ W  (96 cols), el/er via al/ar dot.
// elr layout: [n][0..2]=el(h), [n][3..5]=er(h). kind: 0 = external input
// (dtype per mode), 1 = internal f32 buffer.
// ---------------------------------------------------------------------------
__global__ void ft_elr_kernel(const void* __restrict__ X, int kind, const int* __restrict__ mode,
                              int din, const float* __restrict__ W,
                              const float* __restrict__ al, const float* __restrict__ ar,
                              float* __restrict__ ft, float* __restrict__ elr, int N) {
    __shared__ float xs[8 * 96];
    __shared__ float fs[8 * 96];
    int base = blockIdx.x * 8;
    int t = threadIdx.x;
    int m = *mode;
    for (int i = t; i < 8 * din; i += 256) {
        int ln = i / din, d = i - ln * din;
        int node = base + ln;
        float v = 0.f;
        if (node < N) {
            size_t idx = (size_t)node * din + d;
            if (kind == 1)       v = ((const float*)X)[idx];
            else if (m == 0)     v = b2f(((const bf16*)X)[idx]);
            else                 v = ((const float*)X)[idx];
        }
        xs[ln * 96 + d] = v;
    }
    __syncthreads();
    for (int i = t; i < 768; i += 256) {
        int ln = i / 96, c = i - ln * 96;
        int node = base + ln;
        float acc = 0.f;
        const float* xr = xs + ln * 96;
        for (int d = 0; d < din; ++d) acc += xr[d] * W[d * 96 + c];
        fs[ln * 96 + c] = acc;
        if (node < N) ft[(size_t)node * 96 + c] = acc;
    }
    __syncthreads();
    if (t < 48) {
        int ln = t / 6, q = t - ln * 6;
        int h = q >> 1, isr = q & 1;
        int node = base + ln;
        if (node < N) {
            const float* av = isr ? ar : al;
            const float* fr = fs + ln * 96 + h * 32;
            float acc = 0.f;
            for (int f = 0; f < 32; ++f) acc += fr[f] * av[h * 32 + f];
            elr[node * 6 + isr * 3 + h] = acc;
        }
    }
}

// ---------------------------------------------------------------------------
// Per edge: ee = ef_row @ wae; logit = leaky(el[src]+er[dst]+ee); ex = exp;
// accumulate softmax denominator s[dst][h].
// ---------------------------------------------------------------------------
__global__ void edge_pass_kernel(const void* __restrict__ ef, const int* __restrict__ mode,
                                 const float* __restrict__ wae,
                                 const int* __restrict__ src, const int* __restrict__ dst,
                                 const float* __restrict__ elr,
                                 float* __restrict__ ex, float* __restrict__ s, int E) {
    __shared__ float wsh[96];
    int t = threadIdx.x;
    if (t < 96) wsh[t] = wae[t];
    __syncthreads();
    int e = blockIdx.x * blockDim.x + t;
    if (e >= E) return;
    int m = *mode;

    float x[32];
    if (m == 0) {
        const uint4* p = (const uint4*)((const uint16_t*)ef + (size_t)e * 32);
#pragma unroll
        for (int q = 0; q < 4; ++q) {
            uint4 u = p[q];
            x[q * 8 + 0] = bits2f(u.x << 16); x[q * 8 + 1] = bits2f(u.x & 0xffff0000u);
            x[q * 8 + 2] = bits2f(u.y << 16); x[q * 8 + 3] = bits2f(u.y & 0xffff0000u);
            x[q * 8 + 4] = bits2f(u.z << 16); x[q * 8 + 5] = bits2f(u.z & 0xffff0000u);
            x[q * 8 + 6] = bits2f(u.w << 16); x[q * 8 + 7] = bits2f(u.w & 0xffff0000u);
        }
    } else {
        const float4* p = (const float4*)((const float*)ef + (size_t)e * 32);
#pragma unroll
        for (int q = 0; q < 8; ++q) {
            float4 u = p[q];
            x[q * 4 + 0] = u.x; x[q * 4 + 1] = u.y; x[q * 4 + 2] = u.z; x[q * 4 + 3] = u.w;
        }
    }
    float ee0 = 0.f, ee1 = 0.f, ee2 = 0.f;
#pragma unroll
    for (int d = 0; d < 32; ++d) {
        float xv = x[d];
        ee0 += xv * wsh[d * 3 + 0];
        ee1 += xv * wsh[d * 3 + 1];
        ee2 += xv * wsh[d * 3 + 2];
    }
    int si = src[e], di = dst[e];
    float l0 = elr[si * 6 + 0] + elr[di * 6 + 3] + ee0;
    float l1 = elr[si * 6 + 1] + elr[di * 6 + 4] + ee1;
    float l2 = elr[si * 6 + 2] + elr[di * 6 + 5] + ee2;
    l0 = (l0 > 0.f) ? l0 : 0.2f * l0;
    l1 = (l1 > 0.f) ? l1 : 0.2f * l1;
    l2 = (l2 > 0.f) ? l2 : 0.2f * l2;
    float x0 = __expf(l0), x1 = __expf(l1), x2 = __expf(l2);
    ex[(size_t)e * 3 + 0] = x0;
    ex[(size_t)e * 3 + 1] = x1;
    ex[(size_t)e * 3 + 2] = x2;
    atomicAdd(&s[di * 3 + 0], x0);
    atomicAdd(&s[di * 3 + 1], x1);
    atomicAdd(&s[di * 3 + 2], x2);
}

// rst[dst,:] += ft[src,:] * a[e,h]; 32 lanes per edge.
__global__ void aggregate_kernel(const float* __restrict__ ft, const float* __restrict__ ex,
                                 const float* __restrict__ s,
                                 const int* __restrict__ src, const int* __restrict__ dst,
                                 float* __restrict__ rst, int E) {
    int gid = blockIdx.x * blockDim.x + threadIdx.x;
    int e = gid >> 5;
    int lane = gid & 31;
    if (e >= E) return;
    int si = src[e], di = dst[e];
    size_t fb = (size_t)si * 96, rb = (size_t)di * 96;
#pragma unroll
    for (int k = 0; k < 3; ++k) {
        float a = ex[(size_t)e * 3 + k] / s[di * 3 + k];
        int j = k * 32 + lane;
        atomicAdd(&rst[rb + j], ft[fb + j] * a);
    }
}

__global__ void bias_act_kernel(float* __restrict__ h, const float* __restrict__ b,
                                int total, int do_relu) {
    int i = blockIdx.x * blockDim.x + threadIdx.x;
    if (i >= total) return;
    float v = h[i] + b[i % 96];
    if (do_relu) v = (v > 0.f) ? v : 0.f;
    h[i] = v;
}

// Per node (8/block): u[n,c] = h[n,:]@Wp[0:96,c] + bp[c]; v[n,c] = h[n,:]@Wp[96:,c]
__global__ void uv_kernel(const float* __restrict__ h, const float* __restrict__ Wp,
                          const float* __restrict__ bp, float* __restrict__ uv, int N) {
    __shared__ float hs[8 * 96];
    int base = blockIdx.x * 8;
    int t = threadIdx.x;
    for (int i = t; i < 768; i += 256) {
        int ln = i / 96, c = i - ln * 96;
        int node = base + ln;
        hs[i] = (node < N) ? h[(size_t)node * 96 + c] : 0.f;
    }
    __syncthreads();
    if (t < 160) {
        int ln = t / 20, q = t - ln * 20;
        int half = q / 10, c = q - half * 10;
        int node = base + ln;
        if (node < N) {
            float acc = half ? 0.f : bp[c];
            const float* hr = hs + ln * 96;
            const float* wcol = Wp + half * 960 + c;
            for (int j = 0; j < 96; ++j) acc += hr[j] * wcol[j * 10];
            uv[node * 20 + q] = acc;
        }
    }
}

__global__ void score_kernel(const float* __restrict__ uv, const int* __restrict__ src,
                             const int* __restrict__ dst, const int* __restrict__ mode,
                             void* __restrict__ out, int E) {
    int e = blockIdx.x * blockDim.x + threadIdx.x;
    if (e >= E) return;
    int si = src[e], di = dst[e];
    const float* u = uv + (size_t)si * 20;
    const float* v = uv + (size_t)di * 20 + 10;
    float r[10];
#pragma unroll
    for (int c = 0; c < 10; ++c) r[c] = u[c] + v[c];
    if (*mode == 0) {
        bf16 o[10];
#pragma unroll
        for (int c = 0; c < 10; ++c) o[c] = __float2bfloat16(r[c]);
        uint32_t* po = (uint32_t*)((bf16*)out + (size_t)e * 10);
        const uint32_t* ps = (const uint32_t*)o;
#pragma unroll
        for (int q = 0; q < 5; ++q) po[q] = ps[q];
    } else {
        float2* po = (float2*)((float*)out + (size_t)e * 10);
#pragma unroll
        for (int q = 0; q < 5; ++q) po[q] = make_float2(r[2 * q], r[2 * q + 1]);
    }
}

extern "C" void kernel_launch(void* const* d_in, const int* in_sizes, int n_in,
                              void* d_out, int out_size, void* d_ws, size_t ws_size,
                              hipStream_t stream) {
    const void* nfeats = d_in[0];
    const void* efeats = d_in[1];
    const int* src = (const int*)d_in[2];
    const int* dst = (const int*)d_in[3];

    const int N = in_sizes[0] / 64;
    const int E = in_sizes[2];

    // ---- workspace layout (~99 MB total; fits 128 MiB) ----
    char* w = (char*)d_ws;
    auto alloc = [&](size_t bytes) {
        void* p = (void*)w;
        w += (bytes + 255) & ~(size_t)255;
        return p;
    };
    int*   flag  = (int*)alloc(256);
    float* pbuf  = (float*)alloc((size_t)24202 * 4);       // f32 params
    float* wae   = (float*)alloc(96 * 4);
    float* R     = (float*)alloc((size_t)N * 96 * 4);      // rst / h (in-place)
    float* F     = (float*)alloc((size_t)N * 96 * 4);      // ft (per layer)
    float* ex    = (float*)alloc((size_t)E * 3 * 4);       // also reused as uv
    float* elr   = (float*)alloc((size_t)N * 6 * 4);
    float* sden  = (float*)alloc((size_t)N * 3 * 4);
    float* uv    = ex;                                     // alias: ex dead by then

    // ---- param table: W1,We1,al1,ar1,ae1,b1,W2,We2,al2,ar2,ae2,b2,Wp,bp ----
    const int ns[14] = {64*96, 32*96, 96, 96, 96, 96, 96*96, 32*96, 96, 96, 96, 96, 192*10, 10};
    ParamTable T;
    int off = 0;
    for (int k = 0; k < 14; ++k) { T.src[k] = d_in[4 + k]; T.off[k] = off; off += ns[k]; }
    T.off[14] = off;
    float* W1f  = pbuf + T.off[0];
    float* We1f = pbuf + T.off[1];
    float* al1f = pbuf + T.off[2];
    float* ar1f = pbuf + T.off[3];
    float* ae1f = pbuf + T.off[4];
    float* b1f  = pbuf + T.off[5];
    float* W2f  = pbuf + T.off[6];
    float* We2f = pbuf + T.off[7];
    float* al2f = pbuf + T.off[8];
    float* ar2f = pbuf + T.off[9];
    float* ae2f = pbuf + T.off[10];
    float* b2f_ = pbuf + T.off[11];
    float* Wpf  = pbuf + T.off[12];
    float* bpf  = pbuf + T.off[13];

    dim3 b256(256);
    int eblocks  = (E + 255) / 256;
    int aggBlocks = (int)(((size_t)E * 32 + 255) / 256);
    int naBlocks = (N * 96 + 255) / 256;
    int nodeBlocks = (N + 7) / 8;

    hipLaunchKernelGGL(detect_mode_kernel, dim3(1), dim3(64), 0, stream,
                       (const uint16_t*)nfeats, flag);
    hipLaunchKernelGGL(convert_params_kernel, dim3((off + 255) / 256), b256, 0, stream,
                       T, flag, pbuf);

    // ---- layer 1 ----
    hipLaunchKernelGGL(fold_wae_kernel, dim3(1), dim3(128), 0, stream, We1f, ae1f, wae);
    hipLaunchKernelGGL(ft_elr_kernel, dim3(nodeBlocks), b256, 0, stream,
                       nfeats, 0, flag, 64, W1f, al1f, ar1f, F, elr, N);
    hipMemsetAsync(sden, 0, (size_t)N * 3 * 4, stream);
    hipLaunchKernelGGL(edge_pass_kernel, dim3(eblocks), b256, 0, stream,
                       efeats, flag, wae, src, dst, elr, ex, sden, E);
    hipMemsetAsync(R, 0, (size_t)N * 96 * 4, stream);
    hipLaunchKernelGGL(aggregate_kernel, dim3(aggBlocks), b256, 0, stream,
                       F, ex, sden, src, dst, R, E);
    hipLaunchKernelGGL(bias_act_kernel, dim3(naBlocks), b256, 0, stream,
                       R, b1f, N * 96, 1);

    // ---- layer 2 (R holds h1; consumed by ft_elr, then reused as rst2/h2) ----
    hipLaunchKernelGGL(fold_wae_kernel, dim3(1), dim3(128), 0, stream, We2f, ae2f, wae);
    hipLaunchKernelGGL(ft_elr_kernel, dim3(nodeBlocks), b256, 0, stream,
                       (const void*)R, 1, flag, 96, W2f, al2f, ar2f, F, elr, N);
    hipMemsetAsync(sden, 0, (size_t)N * 3 * 4, stream);
    hipLaunchKernelGGL(edge_pass_kernel, dim3(eblocks), b256, 0, stream,
                       efeats, flag, wae, src, dst, elr, ex, sden, E);
    hipMemsetAsync(R, 0, (size_t)N * 96 * 4, stream);
    hipLaunchKernelGGL(aggregate_kernel, dim3(aggBlocks), b256, 0, stream,
                       F, ex, sden, src, dst, R, E);
    hipLaunchKernelGGL(bias_act_kernel, dim3(naBlocks), b256, 0, stream,
                       R, b2f_, N * 96, 0);

    // ---- predictor ----
    hipLaunchKernelGGL(uv_kernel, dim3(nodeBlocks), b256, 0, stream, R, Wpf, bpf, uv, N);
    hipLaunchKernelGGL(score_kernel, dim3(eblocks), b256, 0, stream,
                       uv, src, dst, flag, d_out, E);
}

// Round 3
// 1312.099 us; speedup vs baseline: 1.6714x; 1.6714x over previous
//
#include <hip/hip_runtime.h>
#include <hip/hip_bf16.h>
#include <stdint.h>

typedef __hip_bfloat16 bf16;

__device__ __forceinline__ float b2f(bf16 x) { return __bfloat162float(x); }
__device__ __forceinline__ float bits2f(uint32_t u) {
    union { uint32_t i; float f; } c; c.i = u; return c.f;
}

// ---------------------------------------------------------------------------
// Mode detection: 0 = bf16 external tensors, 1 = f32. (bf16 confirmed on this
// harness, but keep detection for robustness.)
// ---------------------------------------------------------------------------
__global__ void detect_mode_kernel(const uint16_t* __restrict__ nf, int* __restrict__ flag) {
    if (threadIdx.x != 0 || blockIdx.x != 0) return;
    int sane = 0;
    for (int i = 0; i < 256; ++i) {
        uint32_t u = nf[2 * i];
        float a = fabsf(bits2f(u << 16));
        if (a == 0.f || (a > 1e-5f && a < 100.f)) ++sane;
    }
    flag[0] = (sane >= 128) ? 0 : 1;
}

struct ParamTable {
    const void* src[14];
    int off[15];
};

__global__ void convert_params_kernel(ParamTable T, const int* __restrict__ mode,
                                      float* __restrict__ out) {
    int i = blockIdx.x * blockDim.x + threadIdx.x;
    if (i >= T.off[14]) return;
    int k = 0;
    while (k < 13 && i >= T.off[k + 1]) ++k;
    int j = i - T.off[k];
    out[i] = (*mode == 0) ? b2f(((const bf16*)T.src[k])[j]) : ((const float*)T.src[k])[j];
}

// wae[d*3+h] = sum_f We[d*96 + h*32 + f] * ae[h*32 + f]
__global__ void fold_wae_kernel(const float* __restrict__ We, const float* __restrict__ ae,
                                float* __restrict__ wae) {
    int t = threadIdx.x;
    if (t >= 96) return;
    int d = t / 3, h = t - d * 3;
    float acc = 0.f;
    for (int f = 0; f < 32; ++f) acc += We[d * 96 + h * 32 + f] * ae[h * 32 + f];
    wae[t] = acc;
}

// ---------------------------------------------------------------------------
// CSR build: histogram -> scan -> scatter
// ---------------------------------------------------------------------------
__global__ void hist_kernel(const int* __restrict__ dst, int* __restrict__ cnt, int E) {
    int e = blockIdx.x * blockDim.x + threadIdx.x;
    if (e < E) atomicAdd(&cnt[dst[e]], 1);
}

__global__ void block_sum_kernel(const int* __restrict__ deg, int* __restrict__ bsums, int N) {
    __shared__ int sd[256];
    int t = threadIdx.x;
    int i = blockIdx.x * 256 + t;
    sd[t] = (i < N) ? deg[i] : 0;
    __syncthreads();
    for (int o = 128; o > 0; o >>= 1) {
        if (t < o) sd[t] += sd[t + o];
        __syncthreads();
    }
    if (t == 0) bsums[blockIdx.x] = sd[0];
}

// exclusive scan of bsums in place (nb <= 512)
__global__ void scan_bsums_kernel(int* __restrict__ bsums, int nb) {
    __shared__ int a[512], b[512];
    int t = threadIdx.x;
    int v = (t < nb) ? bsums[t] : 0;
    a[t] = v;
    __syncthreads();
    int* in = a;
    int* out = b;
    for (int o = 1; o < 512; o <<= 1) {
        out[t] = in[t] + ((t >= o) ? in[t - o] : 0);
        __syncthreads();
        int* tmp = in; in = out; out = tmp;
    }
    if (t < nb) bsums[t] = in[t] - v;
}

__global__ void scan_expand_kernel(const int* __restrict__ deg, const int* __restrict__ boffs,
                                   int* __restrict__ row_start, int N) {
    __shared__ int a[256], b[256];
    int t = threadIdx.x;
    int i = blockIdx.x * 256 + t;
    int v = (i < N) ? deg[i] : 0;
    a[t] = v;
    __syncthreads();
    int* in = a;
    int* out = b;
    for (int o = 1; o < 256; o <<= 1) {
        out[t] = in[t] + ((t >= o) ? in[t - o] : 0);
        __syncthreads();
        int* tmp = in; in = out; out = tmp;
    }
    if (i < N) row_start[i] = boffs[blockIdx.x] + in[t] - v;
}

__global__ void set_val_kernel(int* __restrict__ p, int v) { p[0] = v; }

__global__ void scatter_kernel(const int* __restrict__ dst, const int* __restrict__ row_start,
                               int* __restrict__ cur, int* __restrict__ csr_edges, int E) {
    int e = blockIdx.x * blockDim.x + threadIdx.x;
    if (e >= E) return;
    int d = dst[e];
    int p = atomicAdd(&cur[d], 1);
    csr_edges[row_start[d] + p] = e;
}

// ---------------------------------------------------------------------------
// Per node (8/block): ft = x @ W (96 cols), el/er via al/ar dot.
// ---------------------------------------------------------------------------
__global__ void ft_elr_kernel(const void* __restrict__ X, int kind, const int* __restrict__ mode,
                              int din, const float* __restrict__ W,
                              const float* __restrict__ al, const float* __restrict__ ar,
                              float* __restrict__ ft, float* __restrict__ elr, int N) {
    __shared__ float xs[8 * 96];
    __shared__ float fs[8 * 96];
    int base = blockIdx.x * 8;
    int t = threadIdx.x;
    int m = *mode;
    for (int i = t; i < 8 * din; i += 256) {
        int ln = i / din, d = i - ln * din;
        int node = base + ln;
        float v = 0.f;
        if (node < N) {
            size_t idx = (size_t)node * din + d;
            if (kind == 1)   v = ((const float*)X)[idx];
            else if (m == 0) v = b2f(((const bf16*)X)[idx]);
            else             v = ((const float*)X)[idx];
        }
        xs[ln * 96 + d] = v;
    }
    __syncthreads();
    for (int i = t; i < 768; i += 256) {
        int ln = i / 96, c = i - ln * 96;
        int node = base + ln;
        float acc = 0.f;
        const float* xr = xs + ln * 96;
        for (int d = 0; d < din; ++d) acc += xr[d] * W[d * 96 + c];
        fs[ln * 96 + c] = acc;
        if (node < N) ft[(size_t)node * 96 + c] = acc;
    }
    __syncthreads();
    if (t < 48) {
        int ln = t / 6, q = t - ln * 6;
        int h = q >> 1, isr = q & 1;
        int node = base + ln;
        if (node < N) {
            const float* av = isr ? ar : al;
            const float* fr = fs + ln * 96 + h * 32;
            float acc = 0.f;
            for (int f = 0; f < 32; ++f) acc += fr[f] * av[h * 32 + f];
            elr[node * 6 + isr * 3 + h] = acc;
        }
    }
}

// ---------------------------------------------------------------------------
// Per edge: ee = ef_row @ wae; ex = exp(leaky(el[src]+er[dst]+ee)). No atomics.
// ---------------------------------------------------------------------------
__global__ void edge_pass_kernel(const void* __restrict__ ef, const int* __restrict__ mode,
                                 const float* __restrict__ wae,
                                 const int* __restrict__ src, const int* __restrict__ dst,
                                 const float* __restrict__ elr,
                                 float* __restrict__ ex, int E) {
    __shared__ float wsh[96];
    int t = threadIdx.x;
    if (t < 96) wsh[t] = wae[t];
    __syncthreads();
    int e = blockIdx.x * blockDim.x + t;
    if (e >= E) return;
    int m = *mode;

    float x[32];
    if (m == 0) {
        const uint4* p = (const uint4*)((const uint16_t*)ef + (size_t)e * 32);
#pragma unroll
        for (int q = 0; q < 4; ++q) {
            uint4 u = p[q];
            x[q * 8 + 0] = bits2f(u.x << 16); x[q * 8 + 1] = bits2f(u.x & 0xffff0000u);
            x[q * 8 + 2] = bits2f(u.y << 16); x[q * 8 + 3] = bits2f(u.y & 0xffff0000u);
            x[q * 8 + 4] = bits2f(u.z << 16); x[q * 8 + 5] = bits2f(u.z & 0xffff0000u);
            x[q * 8 + 6] = bits2f(u.w << 16); x[q * 8 + 7] = bits2f(u.w & 0xffff0000u);
        }
    } else {
        const float4* p = (const float4*)((const float*)ef + (size_t)e * 32);
#pragma unroll
        for (int q = 0; q < 8; ++q) {
            float4 u = p[q];
            x[q * 4 + 0] = u.x; x[q * 4 + 1] = u.y; x[q * 4 + 2] = u.z; x[q * 4 + 3] = u.w;
        }
    }
    float ee0 = 0.f, ee1 = 0.f, ee2 = 0.f;
#pragma unroll
    for (int d = 0; d < 32; ++d) {
        float xv = x[d];
        ee0 += xv * wsh[d * 3 + 0];
        ee1 += xv * wsh[d * 3 + 1];
        ee2 += xv * wsh[d * 3 + 2];
    }
    int si = src[e], di = dst[e];
    float l0 = elr[si * 6 + 0] + elr[di * 6 + 3] + ee0;
    float l1 = elr[si * 6 + 1] + elr[di * 6 + 4] + ee1;
    float l2 = elr[si * 6 + 2] + elr[di * 6 + 5] + ee2;
    l0 = (l0 > 0.f) ? l0 : 0.2f * l0;
    l1 = (l1 > 0.f) ? l1 : 0.2f * l1;
    l2 = (l2 > 0.f) ? l2 : 0.2f * l2;
    ex[(size_t)e * 3 + 0] = __expf(l0);
    ex[(size_t)e * 3 + 1] = __expf(l1);
    ex[(size_t)e * 3 + 2] = __expf(l2);
}

// ---------------------------------------------------------------------------
// CSR gather aggregation, fused softmax-normalize + bias (+relu).
// 32 lanes per node; lane handles features lane, lane+32, lane+64.
// ---------------------------------------------------------------------------
__global__ void aggregate_csr_kernel(const float* __restrict__ ft, const float* __restrict__ ex,
                                     const int* __restrict__ row_start,
                                     const int* __restrict__ csr_edges,
                                     const int* __restrict__ src,
                                     const float* __restrict__ bias, int do_relu,
                                     float* __restrict__ R, int N) {
    int t = threadIdx.x;
    int node = blockIdx.x * 8 + (t >> 5);
    int lane = t & 31;
    if (node >= N) return;
    int beg = row_start[node], end = row_start[node + 1];
    float a0 = 0.f, a1 = 0.f, a2 = 0.f, s0 = 0.f, s1 = 0.f, s2 = 0.f;
    for (int i = beg; i < end; ++i) {
        int eid = csr_edges[i];
        int sv = src[eid];
        const float* fr = ft + (size_t)sv * 96;
        float e0 = ex[(size_t)eid * 3 + 0];
        float e1 = ex[(size_t)eid * 3 + 1];
        float e2 = ex[(size_t)eid * 3 + 2];
        a0 += fr[lane] * e0;
        a1 += fr[lane + 32] * e1;
        a2 += fr[lane + 64] * e2;
        s0 += e0; s1 += e1; s2 += e2;
    }
    float r0, r1, r2;
    if (end > beg) { r0 = a0 / s0; r1 = a1 / s1; r2 = a2 / s2; }
    else           { r0 = r1 = r2 = 0.f; }
    r0 += bias[lane]; r1 += bias[lane + 32]; r2 += bias[lane + 64];
    if (do_relu) { r0 = fmaxf(r0, 0.f); r1 = fmaxf(r1, 0.f); r2 = fmaxf(r2, 0.f); }
    float* out = R + (size_t)node * 96;
    out[lane] = r0; out[lane + 32] = r1; out[lane + 64] = r2;
}

// Per node (8/block): u[n,c] = h@Wp[0:96,c] + bp[c]; v[n,c] = h@Wp[96:,c]
__global__ void uv_kernel(const float* __restrict__ h, const float* __restrict__ Wp,
                          const float* __restrict__ bp, float* __restrict__ uv, int N) {
    __shared__ float hs[8 * 96];
    int base = blockIdx.x * 8;
    int t = threadIdx.x;
    for (int i = t; i < 768; i += 256) {
        int ln = i / 96, c = i - ln * 96;
        int node = base + ln;
        hs[i] = (node < N) ? h[(size_t)node * 96 + c] : 0.f;
    }
    __syncthreads();
    if (t < 160) {
        int ln = t / 20, q = t - ln * 20;
        int half = q / 10, c = q - half * 10;
        int node = base + ln;
        if (node < N) {
            float acc = half ? 0.f : bp[c];
            const float* hr = hs + ln * 96;
            const float* wcol = Wp + half * 960 + c;
            for (int j = 0; j < 96; ++j) acc += hr[j] * wcol[j * 10];
            uv[node * 20 + q] = acc;
        }
    }
}

__global__ void score_kernel(const float* __restrict__ uv, const int* __restrict__ src,
                             const int* __restrict__ dst, const int* __restrict__ mode,
                             void* __restrict__ out, int E) {
    int e = blockIdx.x * blockDim.x + threadIdx.x;
    if (e >= E) return;
    int si = src[e], di = dst[e];
    const float* u = uv + (size_t)si * 20;
    const float* v = uv + (size_t)di * 20 + 10;
    float r[10];
#pragma unroll
    for (int c = 0; c < 10; ++c) r[c] = u[c] + v[c];
    if (*mode == 0) {
        bf16 o[10];
#pragma unroll
        for (int c = 0; c < 10; ++c) o[c] = __float2bfloat16(r[c]);
        uint32_t* po = (uint32_t*)((bf16*)out + (size_t)e * 10);
        const uint32_t* ps = (const uint32_t*)o;
#pragma unroll
        for (int q = 0; q < 5; ++q) po[q] = ps[q];
    } else {
        float2* po = (float2*)((float*)out + (size_t)e * 10);
#pragma unroll
        for (int q = 0; q < 5; ++q) po[q] = make_float2(r[2 * q], r[2 * q + 1]);
    }
}

extern "C" void kernel_launch(void* const* d_in, const int* in_sizes, int n_in,
                              void* d_out, int out_size, void* d_ws, size_t ws_size,
                              hipStream_t stream) {
    const void* nfeats = d_in[0];
    const void* efeats = d_in[1];
    const int* src = (const int*)d_in[2];
    const int* dst = (const int*)d_in[3];

    const int N = in_sizes[0] / 64;
    const int E = in_sizes[2];

    // ---- workspace (~106 MB) ----
    char* w = (char*)d_ws;
    auto alloc = [&](size_t bytes) {
        void* p = (void*)w;
        w += (bytes + 255) & ~(size_t)255;
        return p;
    };
    int*   flag      = (int*)alloc(256);
    float* pbuf      = (float*)alloc((size_t)24202 * 4);
    float* wae       = (float*)alloc(96 * 4);
    float* R         = (float*)alloc((size_t)N * 96 * 4);   // h (aggregate out, in-place)
    float* F         = (float*)alloc((size_t)N * 96 * 4);   // ft per layer
    float* ex        = (float*)alloc((size_t)E * 3 * 4);    // aliased as uv later
    float* elr       = (float*)alloc((size_t)N * 6 * 4);
    int*   row_start = (int*)alloc((size_t)(N + 1) * 4);
    int*   cnt       = (int*)alloc((size_t)N * 4);          // deg, then cursor
    int*   bsums     = (int*)alloc(512 * 4);
    int*   csr_edges = (int*)alloc((size_t)E * 4);
    float* uv        = ex;

    const int ns[14] = {64*96, 32*96, 96, 96, 96, 96, 96*96, 32*96, 96, 96, 96, 96, 192*10, 10};
    ParamTable T;
    int off = 0;
    for (int k = 0; k < 14; ++k) { T.src[k] = d_in[4 + k]; T.off[k] = off; off += ns[k]; }
    T.off[14] = off;
    float* W1f  = pbuf + T.off[0];
    float* We1f = pbuf + T.off[1];
    float* al1f = pbuf + T.off[2];
    float* ar1f = pbuf + T.off[3];
    float* ae1f = pbuf + T.off[4];
    float* b1f  = pbuf + T.off[5];
    float* W2f  = pbuf + T.off[6];
    float* We2f = pbuf + T.off[7];
    float* al2f = pbuf + T.off[8];
    float* ar2f = pbuf + T.off[9];
    float* ae2f = pbuf + T.off[10];
    float* b2f_ = pbuf + T.off[11];
    float* Wpf  = pbuf + T.off[12];
    float* bpf  = pbuf + T.off[13];

    dim3 b256(256);
    int eblocks    = (E + 255) / 256;
    int nodeBlocks = (N + 7) / 8;
    int nb         = (N + 255) / 256;   // <= 512 for N=100k

    hipLaunchKernelGGL(detect_mode_kernel, dim3(1), dim3(64), 0, stream,
                       (const uint16_t*)nfeats, flag);
    hipLaunchKernelGGL(convert_params_kernel, dim3((off + 255) / 256), b256, 0, stream,
                       T, flag, pbuf);

    // ---- CSR build (once, reused by both layers) ----
    hipMemsetAsync(cnt, 0, (size_t)N * 4, stream);
    hipLaunchKernelGGL(hist_kernel, dim3(eblocks), b256, 0, stream, dst, cnt, E);
    hipLaunchKernelGGL(block_sum_kernel, dim3(nb), b256, 0, stream, cnt, bsums, N);
    hipLaunchKernelGGL(scan_bsums_kernel, dim3(1), dim3(512), 0, stream, bsums, nb);
    hipLaunchKernelGGL(scan_expand_kernel, dim3(nb), b256, 0, stream, cnt, bsums, row_start, N);
    hipLaunchKernelGGL(set_val_kernel, dim3(1), dim3(1), 0, stream, row_start + N, E);
    hipMemsetAsync(cnt, 0, (size_t)N * 4, stream);
    hipLaunchKernelGGL(scatter_kernel, dim3(eblocks), b256, 0, stream,
                       dst, row_start, cnt, csr_edges, E);

    // ---- layer 1 ----
    hipLaunchKernelGGL(fold_wae_kernel, dim3(1), dim3(128), 0, stream, We1f, ae1f, wae);
    hipLaunchKernelGGL(ft_elr_kernel, dim3(nodeBlocks), b256, 0, stream,
                       nfeats, 0, flag, 64, W1f, al1f, ar1f, F, elr, N);
    hipLaunchKernelGGL(edge_pass_kernel, dim3(eblocks), b256, 0, stream,
                       efeats, flag, wae, src, dst, elr, ex, E);
    hipLaunchKernelGGL(aggregate_csr_kernel, dim3(nodeBlocks), b256, 0, stream,
                       F, ex, row_start, csr_edges, src, b1f, 1, R, N);

    // ---- layer 2 ----
    hipLaunchKernelGGL(fold_wae_kernel, dim3(1), dim3(128), 0, stream, We2f, ae2f, wae);
    hipLaunchKernelGGL(ft_elr_kernel, dim3(nodeBlocks), b256, 0, stream,
                       (const void*)R, 1, flag, 96, W2f, al2f, ar2f, F, elr, N);
    hipLaunchKernelGGL(edge_pass_kernel, dim3(eblocks), b256, 0, stream,
                       efeats, flag, wae, src, dst, elr, ex, E);
    hipLaunchKernelGGL(aggregate_csr_kernel, dim3(nodeBlocks), b256, 0, stream,
                       F, ex, row_start, csr_edges, src, b2f_, 0, R, N);

    // ---- predictor ----
    hipLaunchKernelGGL(uv_kernel, dim3(nodeBlocks), b256, 0, stream, R, Wpf, bpf, uv, N);
    hipLaunchKernelGGL(score_kernel, dim3(eblocks), b256, 0, stream,
                       uv, src, dst, flag, d_out, E);
}

// Round 4
// 1182.886 us; speedup vs baseline: 1.8540x; 1.1092x over previous
//
#include <hip/hip_runtime.h>
#include <hip/hip_bf16.h>
#include <stdint.h>

typedef __hip_bfloat16 bf16;

__device__ __forceinline__ float b2f(bf16 x) { return __bfloat162float(x); }
__device__ __forceinline__ float bits2f(uint32_t u) {
    union { uint32_t i; float f; } c; c.i = u; return c.f;
}

// ---------------------------------------------------------------------------
// Mode detection: 0 = bf16 external tensors, 1 = f32.
// ---------------------------------------------------------------------------
__global__ void detect_mode_kernel(const uint16_t* __restrict__ nf, int* __restrict__ flag) {
    if (threadIdx.x != 0 || blockIdx.x != 0) return;
    int sane = 0;
    for (int i = 0; i < 256; ++i) {
        uint32_t u = nf[2 * i];
        float a = fabsf(bits2f(u << 16));
        if (a == 0.f || (a > 1e-5f && a < 100.f)) ++sane;
    }
    flag[0] = (sane >= 128) ? 0 : 1;
}

struct ParamTable {
    const void* src[14];
    int off[15];
};

__global__ void convert_params_kernel(ParamTable T, const int* __restrict__ mode,
                                      float* __restrict__ out) {
    int i = blockIdx.x * blockDim.x + threadIdx.x;
    if (i >= T.off[14]) return;
    int k = 0;
    while (k < 13 && i >= T.off[k + 1]) ++k;
    int j = i - T.off[k];
    out[i] = (*mode == 0) ? b2f(((const bf16*)T.src[k])[j]) : ((const float*)T.src[k])[j];
}

// wae[d*3+h] = sum_f We[d*96 + h*32 + f] * ae[h*32 + f]
__global__ void fold_wae_kernel(const float* __restrict__ We, const float* __restrict__ ae,
                                float* __restrict__ wae) {
    int t = threadIdx.x;
    if (t >= 96) return;
    int d = t / 3, h = t - d * 3;
    float acc = 0.f;
    for (int f = 0; f < 32; ++f) acc += We[d * 96 + h * 32 + f] * ae[h * 32 + f];
    wae[t] = acc;
}

// ---------------------------------------------------------------------------
// CSR build: histogram -> scan -> scatter (also emits csr_src / csr_dst).
// ---------------------------------------------------------------------------
__global__ void hist_kernel(const int* __restrict__ dst, int* __restrict__ cnt, int E) {
    int e = blockIdx.x * blockDim.x + threadIdx.x;
    if (e < E) atomicAdd(&cnt[dst[e]], 1);
}

__global__ void block_sum_kernel(const int* __restrict__ deg, int* __restrict__ bsums, int N) {
    __shared__ int sd[256];
    int t = threadIdx.x;
    int i = blockIdx.x * 256 + t;
    sd[t] = (i < N) ? deg[i] : 0;
    __syncthreads();
    for (int o = 128; o > 0; o >>= 1) {
        if (t < o) sd[t] += sd[t + o];
        __syncthreads();
    }
    if (t == 0) bsums[blockIdx.x] = sd[0];
}

__global__ void scan_bsums_kernel(int* __restrict__ bsums, int nb) {
    __shared__ int a[512], b[512];
    int t = threadIdx.x;
    int v = (t < nb) ? bsums[t] : 0;
    a[t] = v;
    __syncthreads();
    int* in = a;
    int* out = b;
    for (int o = 1; o < 512; o <<= 1) {
        out[t] = in[t] + ((t >= o) ? in[t - o] : 0);
        __syncthreads();
        int* tmp = in; in = out; out = tmp;
    }
    if (t < nb) bsums[t] = in[t] - v;
}

__global__ void scan_expand_kernel(const int* __restrict__ deg, const int* __restrict__ boffs,
                                   int* __restrict__ row_start, int N) {
    __shared__ int a[256], b[256];
    int t = threadIdx.x;
    int i = blockIdx.x * 256 + t;
    int v = (i < N) ? deg[i] : 0;
    a[t] = v;
    __syncthreads();
    int* in = a;
    int* out = b;
    for (int o = 1; o < 256; o <<= 1) {
        out[t] = in[t] + ((t >= o) ? in[t - o] : 0);
        __syncthreads();
        int* tmp = in; in = out; out = tmp;
    }
    if (i < N) row_start[i] = boffs[blockIdx.x] + in[t] - v;
}

__global__ void set_val_kernel(int* __restrict__ p, int v) { p[0] = v; }

__global__ void scatter_kernel(const int* __restrict__ src, const int* __restrict__ dst,
                               const int* __restrict__ row_start, int* __restrict__ cur,
                               int* __restrict__ csr_edges, int* __restrict__ csr_src,
                               int* __restrict__ csr_dst, int E) {
    int e = blockIdx.x * blockDim.x + threadIdx.x;
    if (e >= E) return;
    int d = dst[e];
    int p = atomicAdd(&cur[d], 1);
    int pos = row_start[d] + p;
    csr_edges[pos] = e;
    csr_src[pos] = src[e];
    csr_dst[pos] = d;
}

// ---------------------------------------------------------------------------
// Per node (8/block): ft = x @ W (96 cols), el/er via al/ar dot.
// ---------------------------------------------------------------------------
__global__ void ft_elr_kernel(const void* __restrict__ X, int kind, const int* __restrict__ mode,
                              int din, const float* __restrict__ W,
                              const float* __restrict__ al, const float* __restrict__ ar,
                              float* __restrict__ ft, float* __restrict__ elr, int N) {
    __shared__ float xs[8 * 96];
    __shared__ float fs[8 * 96];
    int base = blockIdx.x * 8;
    int t = threadIdx.x;
    int m = *mode;
    for (int i = t; i < 8 * din; i += 256) {
        int ln = i / din, d = i - ln * din;
        int node = base + ln;
        float v = 0.f;
        if (node < N) {
            size_t idx = (size_t)node * din + d;
            if (kind == 1)   v = ((const float*)X)[idx];
            else if (m == 0) v = b2f(((const bf16*)X)[idx]);
            else             v = ((const float*)X)[idx];
        }
        xs[ln * 96 + d] = v;
    }
    __syncthreads();
    for (int i = t; i < 768; i += 256) {
        int ln = i / 96, c = i - ln * 96;
        int node = base + ln;
        float acc = 0.f;
        const float* xr = xs + ln * 96;
        for (int d = 0; d < din; ++d) acc += xr[d] * W[d * 96 + c];
        fs[ln * 96 + c] = acc;
        if (node < N) ft[(size_t)node * 96 + c] = acc;
    }
    __syncthreads();
    if (t < 48) {
        int ln = t / 6, q = t - ln * 6;
        int h = q >> 1, isr = q & 1;
        int node = base + ln;
        if (node < N) {
            const float* av = isr ? ar : al;
            const float* fr = fs + ln * 96 + h * 32;
            float acc = 0.f;
            for (int f = 0; f < 32; ++f) acc += fr[f] * av[h * 32 + f];
            elr[node * 6 + isr * 3 + h] = acc;
        }
    }
}

// ---------------------------------------------------------------------------
// Edge pass in CSR order: thread i handles csr position i.
// Sequential reads of csr_edges/csr_src/csr_dst; random (but fully-used)
// 64B efeats row; sequential ex[3i] write.
// ---------------------------------------------------------------------------
__global__ void edge_pass_csr_kernel(const void* __restrict__ ef, const int* __restrict__ mode,
                                     const float* __restrict__ wae,
                                     const int* __restrict__ csr_edges,
                                     const int* __restrict__ csr_src,
                                     const int* __restrict__ csr_dst,
                                     const float* __restrict__ elr,
                                     float* __restrict__ ex, int E) {
    __shared__ float wsh[96];
    int t = threadIdx.x;
    if (t < 96) wsh[t] = wae[t];
    __syncthreads();
    int i = blockIdx.x * blockDim.x + t;
    if (i >= E) return;
    int m = *mode;
    int eid = csr_edges[i];
    int si = csr_src[i], di = csr_dst[i];

    float x[32];
    if (m == 0) {
        const uint4* p = (const uint4*)((const uint16_t*)ef + (size_t)eid * 32);
#pragma unroll
        for (int q = 0; q < 4; ++q) {
            uint4 u = p[q];
            x[q * 8 + 0] = bits2f(u.x << 16); x[q * 8 + 1] = bits2f(u.x & 0xffff0000u);
            x[q * 8 + 2] = bits2f(u.y << 16); x[q * 8 + 3] = bits2f(u.y & 0xffff0000u);
            x[q * 8 + 4] = bits2f(u.z << 16); x[q * 8 + 5] = bits2f(u.z & 0xffff0000u);
            x[q * 8 + 6] = bits2f(u.w << 16); x[q * 8 + 7] = bits2f(u.w & 0xffff0000u);
        }
    } else {
        const float4* p = (const float4*)((const float*)ef + (size_t)eid * 32);
#pragma unroll
        for (int q = 0; q < 8; ++q) {
            float4 u = p[q];
            x[q * 4 + 0] = u.x; x[q * 4 + 1] = u.y; x[q * 4 + 2] = u.z; x[q * 4 + 3] = u.w;
        }
    }
    float ee0 = 0.f, ee1 = 0.f, ee2 = 0.f;
#pragma unroll
    for (int d = 0; d < 32; ++d) {
        float xv = x[d];
        ee0 += xv * wsh[d * 3 + 0];
        ee1 += xv * wsh[d * 3 + 1];
        ee2 += xv * wsh[d * 3 + 2];
    }
    float l0 = elr[si * 6 + 0] + elr[di * 6 + 3] + ee0;
    float l1 = elr[si * 6 + 1] + elr[di * 6 + 4] + ee1;
    float l2 = elr[si * 6 + 2] + elr[di * 6 + 5] + ee2;
    l0 = (l0 > 0.f) ? l0 : 0.2f * l0;
    l1 = (l1 > 0.f) ? l1 : 0.2f * l1;
    l2 = (l2 > 0.f) ? l2 : 0.2f * l2;
    ex[(size_t)i * 3 + 0] = __expf(l0);
    ex[(size_t)i * 3 + 1] = __expf(l1);
    ex[(size_t)i * 3 + 2] = __expf(l2);
}

// ---------------------------------------------------------------------------
// CSR gather aggregation (sequential csr_src/ex, random ft rows), unroll x4.
// 32 lanes per node; lane handles features lane, lane+32, lane+64.
// ---------------------------------------------------------------------------
__global__ void aggregate_csr_kernel(const float* __restrict__ ft, const float* __restrict__ ex,
                                     const int* __restrict__ row_start,
                                     const int* __restrict__ csr_src,
                                     const float* __restrict__ bias, int do_relu,
                                     float* __restrict__ R, int N) {
    int t = threadIdx.x;
    int node = blockIdx.x * 8 + (t >> 5);
    int lane = t & 31;
    if (node >= N) return;
    int beg = row_start[node], end = row_start[node + 1];
    float a0 = 0.f, a1 = 0.f, a2 = 0.f, s0 = 0.f, s1 = 0.f, s2 = 0.f;
    int i = beg;
    for (; i + 4 <= end; i += 4) {
        int sv0 = csr_src[i], sv1 = csr_src[i + 1], sv2 = csr_src[i + 2], sv3 = csr_src[i + 3];
        const float* f0 = ft + (size_t)sv0 * 96;
        const float* f1 = ft + (size_t)sv1 * 96;
        const float* f2 = ft + (size_t)sv2 * 96;
        const float* f3 = ft + (size_t)sv3 * 96;
        float v00 = f0[lane], v01 = f0[lane + 32], v02 = f0[lane + 64];
        float v10 = f1[lane], v11 = f1[lane + 32], v12 = f1[lane + 64];
        float v20 = f2[lane], v21 = f2[lane + 32], v22 = f2[lane + 64];
        float v30 = f3[lane], v31 = f3[lane + 32], v32 = f3[lane + 64];
        float e00 = ex[(size_t)i * 3 + 0], e01 = ex[(size_t)i * 3 + 1], e02 = ex[(size_t)i * 3 + 2];
        float e10 = ex[(size_t)i * 3 + 3], e11 = ex[(size_t)i * 3 + 4], e12 = ex[(size_t)i * 3 + 5];
        float e20 = ex[(size_t)i * 3 + 6], e21 = ex[(size_t)i * 3 + 7], e22 = ex[(size_t)i * 3 + 8];
        float e30 = ex[(size_t)i * 3 + 9], e31 = ex[(size_t)i * 3 + 10], e32 = ex[(size_t)i * 3 + 11];
        a0 += v00 * e00 + v10 * e10 + v20 * e20 + v30 * e30;
        a1 += v01 * e01 + v11 * e11 + v21 * e21 + v31 * e31;
        a2 += v02 * e02 + v12 * e12 + v22 * e22 + v32 * e32;
        s0 += e00 + e10 + e20 + e30;
        s1 += e01 + e11 + e21 + e31;
        s2 += e02 + e12 + e22 + e32;
    }
    for (; i < end; ++i) {
        int sv = csr_src[i];
        const float* fr = ft + (size_t)sv * 96;
        float e0 = ex[(size_t)i * 3 + 0];
        float e1 = ex[(size_t)i * 3 + 1];
        float e2 = ex[(size_t)i * 3 + 2];
        a0 += fr[lane] * e0;
        a1 += fr[lane + 32] * e1;
        a2 += fr[lane + 64] * e2;
        s0 += e0; s1 += e1; s2 += e2;
    }
    float r0, r1, r2;
    if (end > beg) { r0 = a0 / s0; r1 = a1 / s1; r2 = a2 / s2; }
    else           { r0 = r1 = r2 = 0.f; }
    r0 += bias[lane]; r1 += bias[lane + 32]; r2 += bias[lane + 64];
    if (do_relu) { r0 = fmaxf(r0, 0.f); r1 = fmaxf(r1, 0.f); r2 = fmaxf(r2, 0.f); }
    float* out = R + (size_t)node * 96;
    out[lane] = r0; out[lane + 32] = r1; out[lane + 64] = r2;
}

// Per node (8/block): u[n,c] = h@Wp[0:96,c] + bp[c]; v[n,c] = h@Wp[96:,c]
__global__ void uv_kernel(const float* __restrict__ h, const float* __restrict__ Wp,
                          const float* __restrict__ bp, float* __restrict__ uv, int N) {
    __shared__ float hs[8 * 96];
    int base = blockIdx.x * 8;
    int t = threadIdx.x;
    for (int i = t; i < 768; i += 256) {
        int ln = i / 96, c = i - ln * 96;
        int node = base + ln;
        hs[i] = (node < N) ? h[(size_t)node * 96 + c] : 0.f;
    }
    __syncthreads();
    if (t < 160) {
        int ln = t / 20, q = t - ln * 20;
        int half = q / 10, c = q - half * 10;
        int node = base + ln;
        if (node < N) {
            float acc = half ? 0.f : bp[c];
            const float* hr = hs + ln * 96;
            const float* wcol = Wp + half * 960 + c;
            for (int j = 0; j < 96; ++j) acc += hr[j] * wcol[j * 10];
            uv[node * 20 + q] = acc;
        }
    }
}

__global__ void score_kernel(const float* __restrict__ uv, const int* __restrict__ src,
                             const int* __restrict__ dst, const int* __restrict__ mode,
                             void* __restrict__ out, int E) {
    int e = blockIdx.x * blockDim.x + threadIdx.x;
    if (e >= E) return;
    int si = src[e], di = dst[e];
    const float* u = uv + (size_t)si * 20;
    const float* v = uv + (size_t)di * 20 + 10;
    float r[10];
#pragma unroll
    for (int c = 0; c < 10; ++c) r[c] = u[c] + v[c];
    if (*mode == 0) {
        bf16 o[10];
#pragma unroll
        for (int c = 0; c < 10; ++c) o[c] = __float2bfloat16(r[c]);
        uint32_t* po = (uint32_t*)((bf16*)out + (size_t)e * 10);
        const uint32_t* ps = (const uint32_t*)o;
#pragma unroll
        for (int q = 0; q < 5; ++q) po[q] = ps[q];
    } else {
        float2* po = (float2*)((float*)out + (size_t)e * 10);
#pragma unroll
        for (int q = 0; q < 5; ++q) po[q] = make_float2(r[2 * q], r[2 * q + 1]);
    }
}

extern "C" void kernel_launch(void* const* d_in, const int* in_sizes, int n_in,
                              void* d_out, int out_size, void* d_ws, size_t ws_size,
                              hipStream_t stream) {
    const void* nfeats = d_in[0];
    const void* efeats = d_in[1];
    const int* src = (const int*)d_in[2];
    const int* dst = (const int*)d_in[3];

    const int N = in_sizes[0] / 64;
    const int E = in_sizes[2];

    // ---- workspace (~119 MB) ----
    char* w = (char*)d_ws;
    auto alloc = [&](size_t bytes) {
        void* p = (void*)w;
        w += (bytes + 255) & ~(size_t)255;
        return p;
    };
    int*   flag      = (int*)alloc(256);
    float* pbuf      = (float*)alloc((size_t)24202 * 4);
    float* wae       = (float*)alloc(96 * 4);
    float* R         = (float*)alloc((size_t)N * 96 * 4);   // h (aggregate out)
    float* F         = (float*)alloc((size_t)N * 96 * 4);   // ft per layer
    float* ex        = (float*)alloc((size_t)E * 3 * 4);    // csr-ordered; aliased as uv
    float* elr       = (float*)alloc((size_t)N * 6 * 4);
    int*   row_start = (int*)alloc((size_t)(N + 1) * 4);
    int*   cnt       = (int*)alloc((size_t)N * 4);
    int*   bsums     = (int*)alloc(512 * 4);
    int*   csr_edges = (int*)alloc((size_t)E * 4);
    int*   csr_src   = (int*)alloc((size_t)E * 4);
    int*   csr_dst   = (int*)alloc((size_t)E * 4);
    float* uv        = ex;

    const int ns[14] = {64*96, 32*96, 96, 96, 96, 96, 96*96, 32*96, 96, 96, 96, 96, 192*10, 10};
    ParamTable T;
    int off = 0;
    for (int k = 0; k < 14; ++k) { T.src[k] = d_in[4 + k]; T.off[k] = off; off += ns[k]; }
    T.off[14] = off;
    float* W1f  = pbuf + T.off[0];
    float* We1f = pbuf + T.off[1];
    float* al1f = pbuf + T.off[2];
    float* ar1f = pbuf + T.off[3];
    float* ae1f = pbuf + T.off[4];
    float* b1f  = pbuf + T.off[5];
    float* W2f  = pbuf + T.off[6];
    float* We2f = pbuf + T.off[7];
    float* al2f = pbuf + T.off[8];
    float* ar2f = pbuf + T.off[9];
    float* ae2f = pbuf + T.off[10];
    float* b2f_ = pbuf + T.off[11];
    float* Wpf  = pbuf + T.off[12];
    float* bpf  = pbuf + T.off[13];

    dim3 b256(256);
    int eblocks    = (E + 255) / 256;
    int nodeBlocks = (N + 7) / 8;
    int nb         = (N + 255) / 256;

    hipLaunchKernelGGL(detect_mode_kernel, dim3(1), dim3(64), 0, stream,
                       (const uint16_t*)nfeats, flag);
    hipLaunchKernelGGL(convert_params_kernel, dim3((off + 255) / 256), b256, 0, stream,
                       T, flag, pbuf);

    // ---- CSR build (once) ----
    hipMemsetAsync(cnt, 0, (size_t)N * 4, stream);
    hipLaunchKernelGGL(hist_kernel, dim3(eblocks), b256, 0, stream, dst, cnt, E);
    hipLaunchKernelGGL(block_sum_kernel, dim3(nb), b256, 0, stream, cnt, bsums, N);
    hipLaunchKernelGGL(scan_bsums_kernel, dim3(1), dim3(512), 0, stream, bsums, nb);
    hipLaunchKernelGGL(scan_expand_kernel, dim3(nb), b256, 0, stream, cnt, bsums, row_start, N);
    hipLaunchKernelGGL(set_val_kernel, dim3(1), dim3(1), 0, stream, row_start + N, E);
    hipMemsetAsync(cnt, 0, (size_t)N * 4, stream);
    hipLaunchKernelGGL(scatter_kernel, dim3(eblocks), b256, 0, stream,
                       src, dst, row_start, cnt, csr_edges, csr_src, csr_dst, E);

    // ---- layer 1 ----
    hipLaunchKernelGGL(fold_wae_kernel, dim3(1), dim3(128), 0, stream, We1f, ae1f, wae);
    hipLaunchKernelGGL(ft_elr_kernel, dim3(nodeBlocks), b256, 0, stream,
                       nfeats, 0, flag, 64, W1f, al1f, ar1f, F, elr, N);
    hipLaunchKernelGGL(edge_pass_csr_kernel, dim3(eblocks), b256, 0, stream,
                       efeats, flag, wae, csr_edges, csr_src, csr_dst, elr, ex, E);
    hipLaunchKernelGGL(aggregate_csr_kernel, dim3(nodeBlocks), b256, 0, stream,
                       F, ex, row_start, csr_src, b1f, 1, R, N);

    // ---- layer 2 ----
    hipLaunchKernelGGL(fold_wae_kernel, dim3(1), dim3(128), 0, stream, We2f, ae2f, wae);
    hipLaunchKernelGGL(ft_elr_kernel, dim3(nodeBlocks), b256, 0, stream,
                       (const void*)R, 1, flag, 96, W2f, al2f, ar2f, F, elr, N);
    hipLaunchKernelGGL(edge_pass_csr_kernel, dim3(eblocks), b256, 0, stream,
                       efeats, flag, wae, csr_edges, csr_src, csr_dst, elr, ex, E);
    hipLaunchKernelGGL(aggregate_csr_kernel, dim3(nodeBlocks), b256, 0, stream,
                       F, ex, row_start, csr_src, b2f_, 0, R, N);

    // ---- predictor ----
    hipLaunchKernelGGL(uv_kernel, dim3(nodeBlocks), b256, 0, stream, R, Wpf, bpf, uv, N);
    hipLaunchKernelGGL(score_kernel, dim3(eblocks), b256, 0, stream,
                       uv, src, dst, flag, d_out, E);
}